// Round 10
// baseline (131.129 us; speedup 1.0000x reference)
//
#include <hip/hip_runtime.h>
#include <hip/hip_bf16.h>

#define Bn 64
#define Cn 128
#define Tn 2048
#define Fn 5
#define Nn 640
#define TCHUNK 256
#define NCHUNK 8                      // 2048/256
#define ROWB (TCHUNK * 2)             // 512 B per bf16 row in LDS

typedef __attribute__((ext_vector_type(8))) short bf16x8;
typedef __attribute__((ext_vector_type(4))) short bf16x4;
typedef __attribute__((ext_vector_type(4))) float f32x4;

// round-to-nearest-even f32 -> bf16
__device__ __forceinline__ short f2bf(float f) {
    union { float f; unsigned u; } v; v.f = f;
    unsigned r = (v.u + 0x7fffu + ((v.u >> 16) & 1u)) >> 16;
    return (short)r;
}

// row stride 512 B; XOR-swizzle rows across 16B slots (G4)
__device__ __forceinline__ int swz(int row, int bytecol) {
    return (row * ROWB + bytecol) ^ ((row & 7) << 4);
}

__device__ __forceinline__ const float* pick_band(const float* d0, const float* d1,
                                                  const float* d2, const float* d3,
                                                  const float* d4, int f) {
    return (f == 0) ? d0 : (f == 1) ? d1 : (f == 2) ? d2 : (f == 3) ? d3 : d4;
}

// R10: 1 KB-contiguous per wave-instruction staging (1 row per instr), 8-deep
// load ILP per thread, only 16 barrier events (8 chunks), 2 blocks/CU
// co-resident. 16 waves in 4x4 grid, 32x32 Gram tile each.
__global__ __launch_bounds__(1024, 8)
void strg_mono(const float* __restrict__ d0, const float* __restrict__ d1,
               const float* __restrict__ d2, const float* __restrict__ d3,
               const float* __restrict__ d4, float* __restrict__ out)
{
    __shared__ __align__(16) char smem[Cn * ROWB];   // 64 KB: bf16 tile; epilogue f32 At overlay
    __shared__ float S_lds[Cn], diag[Cn], mrow[Cn], ivrow[Cn], Dsum[Cn], dinv_s[Cn];

    const int tid = threadIdx.x;
    const int bfid = blockIdx.x;
    const int b = bfid / Fn;
    const int f = bfid - b * Fn;
    const float* src = pick_band(d0, d1, d2, d3, d4, f) + (size_t)b * Cn * Tn;

    if (tid < Cn) { S_lds[tid] = 0.0f; Dsum[tid] = 0.0f; }

    const int lane = tid & 63;
    const int w  = tid >> 6;            // 0..15

    // staging: wave w owns rows w*8 .. w*8+7; one row = 64 lanes x 16 B = 1 KB contiguous
    const int row_o = w * 8;
    const float* tb0 = src + (size_t)row_o * Tn + lane * 4;

    // MFMA mapping: 16 waves in 4x4 grid, each owns a 32x32 tile of the Gram
    const int wr = w >> 2;              // 0..3
    const int wc = w & 3;               // 0..3
    const int r0 = wr * 32;
    const int c0 = wc * 32;
    const int lg = lane >> 4;
    const int ll = lane & 15;

    f32x4 acc[2][2] = {};
    float psum[8] = {};

    for (int ch = 0; ch < NCHUNK; ++ch) {
        // ---- stage: 8 x 1KB-contiguous row reads, 8-deep in flight ----
        const float* cb = tb0 + ch * TCHUNK;
        #pragma unroll
        for (int i = 0; i < 8; ++i) {
            float4 v = *(const float4*)(cb + (size_t)i * Tn);
            psum[i] += v.x + v.y + v.z + v.w;
            bf16x4 h; h[0] = f2bf(v.x); h[1] = f2bf(v.y); h[2] = f2bf(v.z); h[3] = f2bf(v.w);
            *(bf16x4*)(smem + swz(row_o + i, lane * 8)) = h;
        }
        __syncthreads();

        // ---- MFMA over K = 256 ----
        #pragma unroll
        for (int ks = 0; ks < 8; ++ks) {
            bf16x8 afr[2], bfr[2];
            #pragma unroll
            for (int m = 0; m < 2; ++m)
                afr[m] = *(const bf16x8*)(smem + swz(r0 + m * 16 + ll, ks * 64 + lg * 16));
            #pragma unroll
            for (int n = 0; n < 2; ++n)
                bfr[n] = *(const bf16x8*)(smem + swz(c0 + n * 16 + ll, ks * 64 + lg * 16));
            #pragma unroll
            for (int m = 0; m < 2; ++m)
                #pragma unroll
                for (int n = 0; n < 2; ++n)
                    acc[m][n] = __builtin_amdgcn_mfma_f32_16x16x32_bf16(afr[m], bfr[n], acc[m][n], 0, 0, 0);
        }
        __syncthreads();
    }

    // ---- epilogue ----
    // row sums: psum[i] is a full-wave partial for row row_o + i
    #pragma unroll
    for (int i = 0; i < 8; ++i) {
        float s = psum[i];
        s += __shfl_xor(s, 1);
        s += __shfl_xor(s, 2);
        s += __shfl_xor(s, 4);
        s += __shfl_xor(s, 8);
        s += __shfl_xor(s, 16);
        s += __shfl_xor(s, 32);
        if (lane == 0) S_lds[row_o + i] = s;   // unique writer per row
    }

    #pragma unroll
    for (int m = 0; m < 2; ++m)
      #pragma unroll
      for (int n = 0; n < 2; ++n)
        #pragma unroll
        for (int e = 0; e < 4; ++e) {
            const int row = r0 + m * 16 + lg * 4 + e;
            const int col = c0 + n * 16 + ll;
            if (row == col) diag[row] = acc[m][n][e];
        }
    __syncthreads();

    if (tid < Cn) {
        const float S  = S_lds[tid];
        const float mu = S * (1.0f / Tn);
        float var = (diag[tid] - (float)Tn * mu * mu) * (1.0f / (Tn - 1));
        var = var < 0.f ? 0.f : var;
        const float sd = sqrtf(var);
        mrow[tid]  = mu;
        ivrow[tid] = 1.0f / (sd + 1e-8f);
        const size_t ofs = (size_t)Bn * Nn * Nn;
        __builtin_nontemporal_store(var, &out[ofs + (size_t)b * Nn + f * Cn + tid]);
        __builtin_nontemporal_store(var, &out[ofs + (size_t)Bn * Nn + ((size_t)b * Cn + tid) * Fn + f]);
    }
    __syncthreads();

    // a = 0.5*(spa + |corr|) -> LDS A-tile (overlay smem); accumulate row sums
    float* At = (float*)smem;
    {
        float mi[2][4], ii[2][4], mj[2], ij[2];
        #pragma unroll
        for (int m = 0; m < 2; ++m)
          #pragma unroll
          for (int e = 0; e < 4; ++e) {
              const int row = r0 + m * 16 + lg * 4 + e;
              mi[m][e] = mrow[row];
              ii[m][e] = ivrow[row];
          }
        #pragma unroll
        for (int n = 0; n < 2; ++n) {
            const int col = c0 + n * 16 + ll;
            mj[n] = mrow[col];
            ij[n] = ivrow[col];
        }
        const float inv = 1.0f / (Tn - 1);
        #pragma unroll
        for (int m = 0; m < 2; ++m)
          #pragma unroll
          for (int e = 0; e < 4; ++e) {
              const int row = r0 + m * 16 + lg * 4 + e;
              float s = 0.f;
              #pragma unroll
              for (int n = 0; n < 2; ++n) {
                  const int col = c0 + n * 16 + ll;
                  float c = fabsf((acc[m][n][e] - (float)Tn * mi[m][e] * mj[n])
                                  * ii[m][e] * ij[n] * inv);
                  c = (row == col) ? 1.0f : c;
                  const int d = row > col ? row - col : col - row;
                  const float spa = (d >= 1 && d <= 3) ? 1.0f : 0.0f;
                  const float a = 0.5f * (spa + c);
                  At[row * Cn + col] = a;
                  s += a;
              }
              s += __shfl_xor(s, 1);
              s += __shfl_xor(s, 2);
              s += __shfl_xor(s, 4);
              s += __shfl_xor(s, 8);
              if (ll == 0) atomicAdd(&Dsum[row], s);
          }
    }
    __syncthreads();

    if (tid < Cn) dinv_s[tid] = rsqrtf(Dsum[tid] + 1e-8f);
    __syncthreads();

    // write full 128x640 stripe of A_norm (coalesced float4, nontemporal)
    float* Ob = out + (size_t)b * Nn * Nn;
    const int fc = f * Cn;
    for (int e = 0; e < 20; ++e) {
        const int idx4 = e * 4096 + tid * 4;
        const int row = idx4 / Nn;
        const int col = idx4 - row * Nn;
        const int cl = col - fc;
        f32x4 v = {0.f, 0.f, 0.f, 0.f};
        if (cl >= 0 && cl < Cn) {
            const float dr = dinv_s[row];
            v[0] = dr * At[row * Cn + cl]     * dinv_s[cl];
            v[1] = dr * At[row * Cn + cl + 1] * dinv_s[cl + 1];
            v[2] = dr * At[row * Cn + cl + 2] * dinv_s[cl + 2];
            v[3] = dr * At[row * Cn + cl + 3] * dinv_s[cl + 3];
        }
        __builtin_nontemporal_store(v, (f32x4*)(Ob + (size_t)(fc + row) * Nn + col));
    }
}

extern "C" void kernel_launch(void* const* d_in, const int* in_sizes, int n_in,
                              void* d_out, int out_size, void* d_ws, size_t ws_size,
                              hipStream_t stream) {
    const float* d0 = (const float*)d_in[0];
    const float* d1 = (const float*)d_in[1];
    const float* d2 = (const float*)d_in[2];
    const float* d3 = (const float*)d_in[3];
    const float* d4 = (const float*)d_in[4];
    float* out = (float*)d_out;

    strg_mono<<<dim3(Bn * Fn), dim3(1024), 0, stream>>>(d0, d1, d2, d3, d4, out);
}

// Round 11
// 130.927 us; speedup vs baseline: 1.0015x; 1.0015x over previous
//
#include <hip/hip_runtime.h>
#include <hip/hip_bf16.h>

#define Bn 64
#define Cn 128
#define Tn 2048
#define Fn 5
#define Nn 640
#define TCHUNK 64
#define NCHUNK 32
#define BUFBYTES (Cn * TCHUNK * 2)   // 16 KB per bf16 buffer

typedef __attribute__((ext_vector_type(8))) short bf16x8;
typedef __attribute__((ext_vector_type(4))) short bf16x4;
typedef __attribute__((ext_vector_type(4))) float f32x4;

// round-to-nearest-even f32 -> bf16
__device__ __forceinline__ short f2bf(float f) {
    union { float f; unsigned u; } v; v.f = f;
    unsigned r = (v.u + 0x7fffu + ((v.u >> 16) & 1u)) >> 16;
    return (short)r;
}

// bf16 row = 128 B; XOR-swizzle rows across 16B slots (G4; 164K conflicts measured)
__device__ __forceinline__ int swz(int row, int bytecol) {
    return (row * 128 + bytecol) ^ ((row & 7) << 4);
}

__device__ __forceinline__ const float* pick_band(const float* d0, const float* d1,
                                                  const float* d2, const float* d3,
                                                  const float* d4, int f) {
    return (f == 0) ? d0 : (f == 1) ? d1 : (f == 2) ? d2 : (f == 3) ? d3 : d4;
}

// R11 = R4 structure (best bench, 108 us) + zero-region stores INTERLEAVED
// with the main loop: the 512 zero columns of each row-stripe (84 MB chip-wide,
// 80% of all output bytes) depend on nothing — stream them nontemporal, one
// f32x4 store per thread per half-phase, hidden under the read-bound loop.
// Epilogue then writes only the 128x128 diagonal block (8.4 MB).
__global__ __launch_bounds__(512, 4)
void strg_mono(const float* __restrict__ d0, const float* __restrict__ d1,
               const float* __restrict__ d2, const float* __restrict__ d3,
               const float* __restrict__ d4, float* __restrict__ out)
{
    __shared__ __align__(16) char smem[Cn * Cn * 4];   // 64 KB: [0,32K) dbuf; epilogue f32 At
    __shared__ float S_lds[Cn], diag[Cn], mrow[Cn], ivrow[Cn], Dsum[Cn], dinv_s[Cn];

    const int tid = threadIdx.x;
    const int bfid = blockIdx.x;
    const int b = bfid / Fn;
    const int f = bfid - b * Fn;
    const float* src = pick_band(d0, d1, d2, d3, d4, f) + (size_t)b * Cn * Tn;

    if (tid < Cn) { S_lds[tid] = 0.0f; Dsum[tid] = 0.0f; }

    // staging: thread covers rows (srow + 32i), one float4 (16 B) per row at seg sseg
    const int srow = tid >> 4;          // 0..31
    const int sseg = tid & 15;          // 0..15
    const float* tb0 = src + (size_t)srow * Tn + sseg * 4;

    // wave mapping: 8 waves in 4x2 grid, each owns a 32x64 tile of the Gram
    const int lane = tid & 63;
    const int w  = tid >> 6;
    const int wr = w >> 1;
    const int wc = w & 1;
    const int r0 = wr * 32;
    const int c0 = wc * 64;
    const int lg = lane >> 4;
    const int ll = lane & 15;

    // zero-region geometry: per row, 512 zero f32 outside cols [fc, fc+128)
    float* Ob = out + (size_t)b * Nn * Nn;
    const int fc  = f * Cn;
    const int fc4 = f * 32;             // block start in units of f32x4

    f32x4 acc[2][4] = {};
    float psum[4] = {0.f, 0.f, 0.f, 0.f};
    float4 pfA[4], pfB[4];

    auto issueA = [&](int ch) {
        const float* cb = tb0 + ch * TCHUNK;
        #pragma unroll
        for (int i = 0; i < 4; ++i) pfA[i] = *(const float4*)(cb + (size_t)(i * 32) * Tn);
    };
    auto issueB = [&](int ch) {
        const float* cb = tb0 + ch * TCHUNK;
        #pragma unroll
        for (int i = 0; i < 4; ++i) pfB[i] = *(const float4*)(cb + (size_t)(i * 32) * Tn);
    };
    auto convA = [&](int buf) {
        char* base = smem + buf * BUFBYTES;
        #pragma unroll
        for (int i = 0; i < 4; ++i) {
            const int row = i * 32 + srow;
            float4 v = pfA[i];
            psum[i] += v.x + v.y + v.z + v.w;
            bf16x4 hh; hh[0] = f2bf(v.x); hh[1] = f2bf(v.y); hh[2] = f2bf(v.z); hh[3] = f2bf(v.w);
            *(bf16x4*)(base + swz(row, sseg * 8)) = hh;
        }
    };
    auto convB = [&](int buf) {
        char* base = smem + buf * BUFBYTES;
        #pragma unroll
        for (int i = 0; i < 4; ++i) {
            const int row = i * 32 + srow;
            float4 v = pfB[i];
            psum[i] += v.x + v.y + v.z + v.w;
            bf16x4 hh; hh[0] = f2bf(v.x); hh[1] = f2bf(v.y); hh[2] = f2bf(v.z); hh[3] = f2bf(v.w);
            *(bf16x4*)(base + swz(row, sseg * 8)) = hh;
        }
    };
    auto mfma_phase = [&](int buf) {
        const char* base = smem + buf * BUFBYTES;
        #pragma unroll
        for (int ks = 0; ks < 2; ++ks) {
            bf16x8 afr[2], bfr[4];
            #pragma unroll
            for (int m = 0; m < 2; ++m)
                afr[m] = *(const bf16x8*)(base + swz(r0 + m * 16 + ll, ks * 64 + lg * 16));
            #pragma unroll
            for (int n = 0; n < 4; ++n)
                bfr[n] = *(const bf16x8*)(base + swz(c0 + n * 16 + ll, ks * 64 + lg * 16));
            #pragma unroll
            for (int m = 0; m < 2; ++m)
                #pragma unroll
                for (int n = 0; n < 4; ++n)
                    acc[m][n] = __builtin_amdgcn_mfma_f32_16x16x32_bf16(afr[m], bfr[n], acc[m][n], 0, 0, 0);
        }
    };
    // one nontemporal f32x4 zero-store per thread per half-phase j (j = 0..31)
    auto zstore = [&](int j) {
        const int zidx = j * 512 + tid;          // 0..16383 = 128 rows x 128 vec4
        const int row = zidx >> 7;
        const int v   = zidx & 127;
        const int col4 = (v < fc4) ? v : (v + 32);   // skip the diagonal block
        const f32x4 z = {0.f, 0.f, 0.f, 0.f};
        __builtin_nontemporal_store(z, (f32x4*)(Ob + (size_t)(fc + row) * Nn + col4 * 4));
    };

    // prologue: chunk0 staged in buf0; chunk1 (B) and chunk2 (A) in flight
    issueA(0);
    issueB(1);
    convA(0);
    issueA(2);
    asm volatile("s_waitcnt lgkmcnt(0)" ::: "memory");
    __builtin_amdgcn_s_barrier();
    __builtin_amdgcn_sched_barrier(0);

    for (int k = 0; k < NCHUNK; k += 2) {
        convB(1);                                   // loads 2 half-phases old
        if (k + 3 < NCHUNK) issueB(k + 3);
        mfma_phase(0);
        zstore(k);                                  // fire-and-forget zero stores
        asm volatile("s_waitcnt lgkmcnt(0)" ::: "memory");
        __builtin_amdgcn_s_barrier();               // raw: vmcnt lives across
        __builtin_amdgcn_sched_barrier(0);

        if (k + 2 < NCHUNK) {
            convA(0);
            if (k + 4 < NCHUNK) issueA(k + 4);
        }
        mfma_phase(1);
        zstore(k + 1);
        asm volatile("s_waitcnt lgkmcnt(0)" ::: "memory");
        __builtin_amdgcn_s_barrier();
        __builtin_amdgcn_sched_barrier(0);
    }

    // ---- epilogue ----
    #pragma unroll
    for (int i = 0; i < 4; ++i)
        atomicAdd(&S_lds[i * 32 + srow], psum[i]);

    #pragma unroll
    for (int m = 0; m < 2; ++m)
      #pragma unroll
      for (int n = 0; n < 4; ++n)
        #pragma unroll
        for (int e = 0; e < 4; ++e) {
            const int row = r0 + m * 16 + lg * 4 + e;
            const int col = c0 + n * 16 + ll;
            if (row == col) diag[row] = acc[m][n][e];
        }
    __syncthreads();

    if (tid < Cn) {
        const float S  = S_lds[tid];
        const float mu = S * (1.0f / Tn);
        float var = (diag[tid] - (float)Tn * mu * mu) * (1.0f / (Tn - 1));
        var = var < 0.f ? 0.f : var;
        const float sd = sqrtf(var);
        mrow[tid]  = mu;
        ivrow[tid] = 1.0f / (sd + 1e-8f);
        const size_t ofs = (size_t)Bn * Nn * Nn;
        __builtin_nontemporal_store(var, &out[ofs + (size_t)b * Nn + f * Cn + tid]);
        __builtin_nontemporal_store(var, &out[ofs + (size_t)Bn * Nn + ((size_t)b * Cn + tid) * Fn + f]);
    }
    __syncthreads();

    // a = 0.5*(spa + |corr|) -> LDS A-tile (reuse smem); accumulate row sums
    float* At = (float*)smem;
    {
        float mi[2][4], ii[2][4], mj[4], ij[4];
        #pragma unroll
        for (int m = 0; m < 2; ++m)
          #pragma unroll
          for (int e = 0; e < 4; ++e) {
              const int row = r0 + m * 16 + lg * 4 + e;
              mi[m][e] = mrow[row];
              ii[m][e] = ivrow[row];
          }
        #pragma unroll
        for (int n = 0; n < 4; ++n) {
            const int col = c0 + n * 16 + ll;
            mj[n] = mrow[col];
            ij[n] = ivrow[col];
        }
        const float inv = 1.0f / (Tn - 1);
        #pragma unroll
        for (int m = 0; m < 2; ++m)
          #pragma unroll
          for (int e = 0; e < 4; ++e) {
              const int row = r0 + m * 16 + lg * 4 + e;
              float s = 0.f;
              #pragma unroll
              for (int n = 0; n < 4; ++n) {
                  const int col = c0 + n * 16 + ll;
                  float c = fabsf((acc[m][n][e] - (float)Tn * mi[m][e] * mj[n])
                                  * ii[m][e] * ij[n] * inv);
                  c = (row == col) ? 1.0f : c;
                  const int d = row > col ? row - col : col - row;
                  const float spa = (d >= 1 && d <= 3) ? 1.0f : 0.0f;
                  const float a = 0.5f * (spa + c);
                  At[row * Cn + col] = a;
                  s += a;
              }
              s += __shfl_xor(s, 1);
              s += __shfl_xor(s, 2);
              s += __shfl_xor(s, 4);
              s += __shfl_xor(s, 8);
              if (ll == 0) atomicAdd(&Dsum[row], s);
          }
    }
    __syncthreads();

    if (tid < Cn) dinv_s[tid] = rsqrtf(Dsum[tid] + 1e-8f);
    __syncthreads();

    // write ONLY the 128x128 diagonal block (zeros already streamed in-loop)
    for (int e = 0; e < 8; ++e) {
        const int idx4 = e * 512 + tid;          // 0..4095 = 128 rows x 32 vec4
        const int row = idx4 >> 5;
        const int c4  = idx4 & 31;
        const int cl  = c4 * 4;
        const float dr = dinv_s[row];
        f32x4 v;
        v[0] = dr * At[row * Cn + cl]     * dinv_s[cl];
        v[1] = dr * At[row * Cn + cl + 1] * dinv_s[cl + 1];
        v[2] = dr * At[row * Cn + cl + 2] * dinv_s[cl + 2];
        v[3] = dr * At[row * Cn + cl + 3] * dinv_s[cl + 3];
        __builtin_nontemporal_store(v, (f32x4*)(Ob + (size_t)(fc + row) * Nn + fc + cl));
    }
}

extern "C" void kernel_launch(void* const* d_in, const int* in_sizes, int n_in,
                              void* d_out, int out_size, void* d_ws, size_t ws_size,
                              hipStream_t stream) {
    const float* d0 = (const float*)d_in[0];
    const float* d1 = (const float*)d_in[1];
    const float* d2 = (const float*)d_in[2];
    const float* d3 = (const float*)d_in[3];
    const float* d4 = (const float*)d_in[4];
    float* out = (float*)d_out;

    strg_mono<<<dim3(Bn * Fn), dim3(512), 0, stream>>>(d0, d1, d2, d3, d4, out);
}

// Round 12
// 108.943 us; speedup vs baseline: 1.2036x; 1.2018x over previous
//
#include <hip/hip_runtime.h>
#include <hip/hip_bf16.h>

#define Bn 64
#define Cn 128
#define Tn 2048
#define Fn 5
#define Nn 640
#define TCHUNK 64
#define NCHUNK 32
#define BUFBYTES (Cn * TCHUNK * 2)   // 16 KB per bf16 buffer

typedef __attribute__((ext_vector_type(8))) short bf16x8;
typedef __attribute__((ext_vector_type(4))) short bf16x4;
typedef __attribute__((ext_vector_type(4))) float f32x4;

// round-to-nearest-even f32 -> bf16 (finite inputs)
__device__ __forceinline__ short f2bf(float f) {
    union { float f; unsigned u; } v; v.f = f;
    unsigned r = (v.u + 0x7fffu + ((v.u >> 16) & 1u)) >> 16;
    return (short)r;
}

// bf16 row = 128 B; XOR-swizzle rows across 16B slots (G4). Bank period = 128 B.
__device__ __forceinline__ int swz(int row, int bytecol) {
    return (row * 128 + bytecol) ^ ((row & 7) << 4);
}

__device__ __forceinline__ const float* pick_band(const float* d0, const float* d1,
                                                  const float* d2, const float* d3,
                                                  const float* d4, int f) {
    return (f == 0) ? d0 : (f == 1) ? d1 : (f == 2) ? d2 : (f == 3) ? d3 : d4;
}

// FINAL (= R4, best measured: 108.2 us bench). One block per (b,f). Depth-3
// register prefetch (2 named sets), convert-before-MFMA, raw s_barrier with
// lgkmcnt-only drain (global loads stay in flight across 2 full iterations).
// Epilogue writes the full 128x640 A_norm stripe (no memset pass).
// Measured: FETCH 164 MB (L3 absorbs ~half the 335 MB input re-reads),
// WRITE 103 MB, bank conflicts 164K, ~4.1 TB/s app-level in timed replays
// (80% of this chip's measured 5 TB/s streaming ceiling, k1 probe R8).
__global__ __launch_bounds__(512, 4)
void strg_mono(const float* __restrict__ d0, const float* __restrict__ d1,
               const float* __restrict__ d2, const float* __restrict__ d3,
               const float* __restrict__ d4, float* __restrict__ out)
{
    __shared__ __align__(16) char smem[Cn * Cn * 4];   // 64 KB: loop uses [0,32K) as dbuf; epilogue = f32 A-tile
    __shared__ float S_lds[Cn], diag[Cn], mrow[Cn], ivrow[Cn], Dsum[Cn], dinv_s[Cn];

    const int tid = threadIdx.x;
    const int bfid = blockIdx.x;
    const int b = bfid / Fn;
    const int f = bfid - b * Fn;
    const float* src = pick_band(d0, d1, d2, d3, d4, f) + (size_t)b * Cn * Tn;

    if (tid < Cn) { S_lds[tid] = 0.0f; Dsum[tid] = 0.0f; }

    // staging: thread covers rows (srow + 32i), one float4 (16 B) per row at seg sseg
    const int srow = tid >> 4;          // 0..31
    const int sseg = tid & 15;          // 0..15
    const float* tb0 = src + (size_t)srow * Tn + sseg * 4;

    // wave mapping: 8 waves in 4x2 grid, each owns a 32x64 tile of the Gram
    const int lane = tid & 63;
    const int w  = tid >> 6;
    const int wr = w >> 1;
    const int wc = w & 1;
    const int r0 = wr * 32;
    const int c0 = wc * 64;
    const int lg = lane >> 4;
    const int ll = lane & 15;

    f32x4 acc[2][4] = {};
    float psum[4] = {0.f, 0.f, 0.f, 0.f};
    float4 pfA[4], pfB[4];

    auto issueA = [&](int ch) {
        const float* cb = tb0 + ch * TCHUNK;
        #pragma unroll
        for (int i = 0; i < 4; ++i) pfA[i] = *(const float4*)(cb + (size_t)(i * 32) * Tn);
    };
    auto issueB = [&](int ch) {
        const float* cb = tb0 + ch * TCHUNK;
        #pragma unroll
        for (int i = 0; i < 4; ++i) pfB[i] = *(const float4*)(cb + (size_t)(i * 32) * Tn);
    };
    auto convA = [&](int buf) {
        char* base = smem + buf * BUFBYTES;
        #pragma unroll
        for (int i = 0; i < 4; ++i) {
            const int row = i * 32 + srow;
            float4 v = pfA[i];
            psum[i] += v.x + v.y + v.z + v.w;
            bf16x4 h; h[0] = f2bf(v.x); h[1] = f2bf(v.y); h[2] = f2bf(v.z); h[3] = f2bf(v.w);
            *(bf16x4*)(base + swz(row, sseg * 8)) = h;
        }
    };
    auto convB = [&](int buf) {
        char* base = smem + buf * BUFBYTES;
        #pragma unroll
        for (int i = 0; i < 4; ++i) {
            const int row = i * 32 + srow;
            float4 v = pfB[i];
            psum[i] += v.x + v.y + v.z + v.w;
            bf16x4 h; h[0] = f2bf(v.x); h[1] = f2bf(v.y); h[2] = f2bf(v.z); h[3] = f2bf(v.w);
            *(bf16x4*)(base + swz(row, sseg * 8)) = h;
        }
    };
    auto mfma_phase = [&](int buf) {
        const char* base = smem + buf * BUFBYTES;
        #pragma unroll
        for (int ks = 0; ks < 2; ++ks) {
            bf16x8 afr[2], bfr[4];
            #pragma unroll
            for (int m = 0; m < 2; ++m)
                afr[m] = *(const bf16x8*)(base + swz(r0 + m * 16 + ll, ks * 64 + lg * 16));
            #pragma unroll
            for (int n = 0; n < 4; ++n)
                bfr[n] = *(const bf16x8*)(base + swz(c0 + n * 16 + ll, ks * 64 + lg * 16));
            #pragma unroll
            for (int m = 0; m < 2; ++m)
                #pragma unroll
                for (int n = 0; n < 4; ++n)
                    acc[m][n] = __builtin_amdgcn_mfma_f32_16x16x32_bf16(afr[m], bfr[n], acc[m][n], 0, 0, 0);
        }
    };

    // prologue: chunk0 staged in buf0; chunk1 (B) and chunk2 (A) in flight
    issueA(0);
    issueB(1);
    convA(0);                 // compiler waits vmcnt for pfA uses; pfB stays outstanding
    issueA(2);
    asm volatile("s_waitcnt lgkmcnt(0)" ::: "memory");
    __builtin_amdgcn_s_barrier();
    __builtin_amdgcn_sched_barrier(0);

    for (int k = 0; k < NCHUNK; k += 2) {
        // consume chunk k from buf0; stage chunk k+1 (set B) into buf1
        convB(1);                                   // loads 2 iterations old
        if (k + 3 < NCHUNK) issueB(k + 3);
        mfma_phase(0);
        asm volatile("s_waitcnt lgkmcnt(0)" ::: "memory");
        __builtin_amdgcn_s_barrier();               // raw: vmcnt NOT drained
        __builtin_amdgcn_sched_barrier(0);

        // consume chunk k+1 from buf1; stage chunk k+2 (set A) into buf0
        if (k + 2 < NCHUNK) {
            convA(0);
            if (k + 4 < NCHUNK) issueA(k + 4);
        }
        mfma_phase(1);
        asm volatile("s_waitcnt lgkmcnt(0)" ::: "memory");
        __builtin_amdgcn_s_barrier();
        __builtin_amdgcn_sched_barrier(0);
    }

    // ---- epilogue ----
    #pragma unroll
    for (int i = 0; i < 4; ++i)
        atomicAdd(&S_lds[i * 32 + srow], psum[i]);

    #pragma unroll
    for (int m = 0; m < 2; ++m)
      #pragma unroll
      for (int n = 0; n < 4; ++n)
        #pragma unroll
        for (int e = 0; e < 4; ++e) {
            const int row = r0 + m * 16 + lg * 4 + e;
            const int col = c0 + n * 16 + ll;
            if (row == col) diag[row] = acc[m][n][e];
        }
    __syncthreads();

    if (tid < Cn) {
        const float S  = S_lds[tid];
        const float mu = S * (1.0f / Tn);
        float var = (diag[tid] - (float)Tn * mu * mu) * (1.0f / (Tn - 1));
        var = var < 0.f ? 0.f : var;
        const float sd = sqrtf(var);
        mrow[tid]  = mu;
        ivrow[tid] = 1.0f / (sd + 1e-8f);
        const size_t ofs = (size_t)Bn * Nn * Nn;
        out[ofs + (size_t)b * Nn + f * Cn + tid] = var;                      // node_features
        out[ofs + (size_t)Bn * Nn + ((size_t)b * Cn + tid) * Fn + f] = var;  // bandpowers
    }
    __syncthreads();

    // a = 0.5*(spa + |corr|) -> LDS A-tile (reuse smem); accumulate row sums
    float* At = (float*)smem;
    {
        float mi[2][4], ii[2][4], mj[4], ij[4];
        #pragma unroll
        for (int m = 0; m < 2; ++m)
          #pragma unroll
          for (int e = 0; e < 4; ++e) {
              const int row = r0 + m * 16 + lg * 4 + e;
              mi[m][e] = mrow[row];
              ii[m][e] = ivrow[row];
          }
        #pragma unroll
        for (int n = 0; n < 4; ++n) {
            const int col = c0 + n * 16 + ll;
            mj[n] = mrow[col];
            ij[n] = ivrow[col];
        }
        const float inv = 1.0f / (Tn - 1);
        #pragma unroll
        for (int m = 0; m < 2; ++m)
          #pragma unroll
          for (int e = 0; e < 4; ++e) {
              const int row = r0 + m * 16 + lg * 4 + e;
              float s = 0.f;
              #pragma unroll
              for (int n = 0; n < 4; ++n) {
                  const int col = c0 + n * 16 + ll;
                  float c = fabsf((acc[m][n][e] - (float)Tn * mi[m][e] * mj[n])
                                  * ii[m][e] * ij[n] * inv);
                  c = (row == col) ? 1.0f : c;
                  const int d = row > col ? row - col : col - row;
                  const float spa = (d >= 1 && d <= 3) ? 1.0f : 0.0f;
                  const float a = 0.5f * (spa + c);
                  At[row * Cn + col] = a;
                  s += a;
              }
              s += __shfl_xor(s, 1);
              s += __shfl_xor(s, 2);
              s += __shfl_xor(s, 4);
              s += __shfl_xor(s, 8);
              if (ll == 0) atomicAdd(&Dsum[row], s);
          }
    }
    __syncthreads();

    if (tid < Cn) dinv_s[tid] = rsqrtf(Dsum[tid] + 1e-8f);
    __syncthreads();

    // write full 128x640 stripe of A_norm (coalesced float4, zeros outside block)
    float* Ob = out + (size_t)b * Nn * Nn;
    const int fc = f * Cn;
    for (int e = 0; e < 40; ++e) {
        const int idx4 = e * 2048 + tid * 4;
        const int row = idx4 / Nn;
        const int col = idx4 - row * Nn;
        const int cl = col - fc;
        float4 v = {0.f, 0.f, 0.f, 0.f};
        if (cl >= 0 && cl < Cn) {
            const float dr = dinv_s[row];
            v.x = dr * At[row * Cn + cl]     * dinv_s[cl];
            v.y = dr * At[row * Cn + cl + 1] * dinv_s[cl + 1];
            v.z = dr * At[row * Cn + cl + 2] * dinv_s[cl + 2];
            v.w = dr * At[row * Cn + cl + 3] * dinv_s[cl + 3];
        }
        *(float4*)(Ob + (size_t)(fc + row) * Nn + col) = v;
    }
}

extern "C" void kernel_launch(void* const* d_in, const int* in_sizes, int n_in,
                              void* d_out, int out_size, void* d_ws, size_t ws_size,
                              hipStream_t stream) {
    const float* d0 = (const float*)d_in[0];
    const float* d1 = (const float*)d_in[1];
    const float* d2 = (const float*)d_in[2];
    const float* d3 = (const float*)d_in[3];
    const float* d4 = (const float*)d_in[4];
    float* out = (float*)d_out;

    strg_mono<<<dim3(Bn * Fn), dim3(512), 0, stream>>>(d0, d1, d2, d3, d4, out);
}